// Round 21
// baseline (552.759 us; speedup 1.0000x reference)
//
#include <hip/hip_runtime.h>
#include <hip/hip_bf16.h>

// GNODE fully fused: y' = relu(y@W1+b1)@W2+b2, RK4(3/8) x10 steps (h=0.1),
// out = y@Wl+bl.  N=200000 rows, 128 ch, 64 out ch.
//
// Round 21 = r20 (32x32x16 MFMA, 4-way split, layout verified, 526us) with
// U/V state PACKED to bf16 pairs.  r20's regression vs r17 was occupancy:
// VGPR 100 arch + 80 AGPR = 180 > 170 -> 2 waves/SIMD.  Packing U/V saves
// 16 arch regs -> ~84 + 80 = 164 < 170 -> 3 waves/SIMD (r17's level) while
// keeping r20's halved per-row VALU/barriers and +15% MFMA rate.
// Packed-U/V numerics validated in r10/r16 (absmax 0.0156 unchanged).
//
// Block = 256 thr = 4 waves, 32 rows; wave wid owns out-ch [32wid,+32) of
// both layers.  Weights 8+8 A-frags = 64 regs (AGPR-resident).
// Layouts (32x32x16 bf16):
//   C/D (HW-verified m74/m101): col(batch) = lane&31,
//        row(ch_local) = (reg&3) + 8*(reg>>2) + 4*(lane>>5), reg in [0,16)
//   A/B operand (verified by r20 passing): elem j of 8:
//        k = 16*kw + 8*(j>>2) + 4*(lane>>5) + (j&3)
//   => B-frag window t: frag[t][j] = state[8t+j]; acc reg order == state
//      order.  All lane-local.
// Exchange: wave writes windows 2wid,2wid+1 (b128), reads other 6; all
// lane-contiguous b128 -> conflict-free.  2 barriers/feval, alternating
// buffers (argx, hx) -> WAR-safe.
//
// State recurrences (template<MODE>):
//   M1: U<-k1   M2: V<-k2   M3: U<-U+3(V+k3), V<-U-V+k3   M4: y+=h/8(U+k4)

typedef __attribute__((ext_vector_type(8))) short bf16x8;
typedef __attribute__((ext_vector_type(4))) float f32x4;
typedef __attribute__((ext_vector_type(16))) float f32x16;

constexpr float HS = 0.1f;

__device__ __forceinline__ short bf16s(float f) {
    return __builtin_bit_cast(short, (__bf16)f);      // -> v_cvt_pk_bf16_f32 (paired)
}
__device__ __forceinline__ bf16x8 bc8(uint4 u) { return __builtin_bit_cast(bf16x8, u); }
__device__ __forceinline__ float bplo(unsigned u) { return __builtin_bit_cast(float, u << 16); }
__device__ __forceinline__ float bphi(unsigned u) { return __builtin_bit_cast(float, u & 0xffff0000u); }
__device__ __forceinline__ unsigned packbf(float a, float b) {
    unsigned ua = (unsigned)__builtin_bit_cast(unsigned short, (__bf16)a);
    unsigned ub = (unsigned)__builtin_bit_cast(unsigned short, (__bf16)b);
    return ua | (ub << 16);
}

#define MFMA32 __builtin_amdgcn_mfma_f32_32x32x16_bf16

// B-frag for window t (0/1) from y(fp32) + packed-bf16 U/V.
template<int M>
__device__ __forceinline__ bf16x8 build_frag(const float (&y)[16], const unsigned (&Up)[8],
                                             const unsigned (&Vp)[8], int t) {
    bf16x8 f;
    #pragma unroll
    for (int j = 0; j < 8; ++j) {
        const int e = t * 8 + j;
        const float Ue = (e & 1) ? bphi(Up[e >> 1]) : bplo(Up[e >> 1]);
        const float Ve = (e & 1) ? bphi(Vp[e >> 1]) : bplo(Vp[e >> 1]);
        float v;
        if (M == 1)      v = y[e];
        else if (M == 2) v = fmaf(HS * (1.f / 3.f), Ue, y[e]);
        else if (M == 3) v = fmaf(-HS * (1.f / 3.f), Ue, fmaf(HS, Ve, y[e]));
        else             v = fmaf(HS, Ve, y[e]);
        f[j] = bf16s(v);
    }
    return f;
}

// One f-eval for this wave's 32-out-ch slice (32 batch rows).
// Weight frags wid-relative: w[kl] = global window (2wid+kl)&7.
template<int M>
__device__ __forceinline__ void feval(const bf16x8 (&w1r)[8], const bf16x8 (&w2r)[8],
                                      const float* __restrict__ sbf1,
                                      const float* __restrict__ sbf2,
                                      uint4* __restrict__ myA,
                                      const uint4* const (&oa)[6],
                                      uint4* __restrict__ myH,
                                      const uint4* const (&oh)[6],
                                      float (&y)[16], unsigned (&Up)[8], unsigned (&Vp)[8])
{
    // ---- own 2 arg windows -> LDS; bias init overlaps the barrier
    const bf16x8 a0 = build_frag<M>(y, Up, Vp, 0);
    const bf16x8 a1 = build_frag<M>(y, Up, Vp, 1);
    myA[0]  = __builtin_bit_cast(uint4, a0);
    myA[64] = __builtin_bit_cast(uint4, a1);
    f32x16 acc;
    #pragma unroll
    for (int q = 0; q < 4; ++q) {
        const f32x4 b = *(const f32x4*)&sbf1[8 * q];
        #pragma unroll
        for (int r = 0; r < 4; ++r) acc[4 * q + r] = b[r];
    }
    __syncthreads();
    const bf16x8 e2 = bc8(*oa[0]), e3 = bc8(*oa[1]), e4 = bc8(*oa[2]);
    const bf16x8 e5 = bc8(*oa[3]), e6 = bc8(*oa[4]), e7 = bc8(*oa[5]);

    // ---- matmul1: 8 MFMA (windows in wid-relative order)
    __builtin_amdgcn_s_setprio(1);
    acc = MFMA32(w1r[0], a0, acc, 0, 0, 0);
    acc = MFMA32(w1r[1], a1, acc, 0, 0, 0);
    acc = MFMA32(w1r[2], e2, acc, 0, 0, 0);
    acc = MFMA32(w1r[3], e3, acc, 0, 0, 0);
    acc = MFMA32(w1r[4], e4, acc, 0, 0, 0);
    acc = MFMA32(w1r[5], e5, acc, 0, 0, 0);
    acc = MFMA32(w1r[6], e6, acc, 0, 0, 0);
    acc = MFMA32(w1r[7], e7, acc, 0, 0, 0);
    __builtin_amdgcn_s_setprio(0);

    // ---- relu -> own h windows (acc reg order == state order)
    bf16x8 h0, h1;
    #pragma unroll
    for (int j = 0; j < 8; ++j) {
        h0[j] = bf16s(fmaxf(acc[j], 0.f));
        h1[j] = bf16s(fmaxf(acc[8 + j], 0.f));
    }
    myH[0]  = __builtin_bit_cast(uint4, h0);
    myH[64] = __builtin_bit_cast(uint4, h1);
    f32x16 acc2;
    #pragma unroll
    for (int q = 0; q < 4; ++q) {
        const f32x4 b = *(const f32x4*)&sbf2[8 * q];
        #pragma unroll
        for (int r = 0; r < 4; ++r) acc2[4 * q + r] = b[r];
    }
    __syncthreads();
    const bf16x8 f2 = bc8(*oh[0]), f3 = bc8(*oh[1]), f4 = bc8(*oh[2]);
    const bf16x8 f5 = bc8(*oh[3]), f6 = bc8(*oh[4]), f7 = bc8(*oh[5]);

    // ---- matmul2: 8 MFMA
    __builtin_amdgcn_s_setprio(1);
    acc2 = MFMA32(w2r[0], h0, acc2, 0, 0, 0);
    acc2 = MFMA32(w2r[1], h1, acc2, 0, 0, 0);
    acc2 = MFMA32(w2r[2], f2, acc2, 0, 0, 0);
    acc2 = MFMA32(w2r[3], f3, acc2, 0, 0, 0);
    acc2 = MFMA32(w2r[4], f4, acc2, 0, 0, 0);
    acc2 = MFMA32(w2r[5], f5, acc2, 0, 0, 0);
    acc2 = MFMA32(w2r[6], f6, acc2, 0, 0, 0);
    acc2 = MFMA32(w2r[7], f7, acc2, 0, 0, 0);
    __builtin_amdgcn_s_setprio(0);

    // ---- mode-fused writeback (pair p covers regs 2p,2p+1 - adjacent)
    #pragma unroll
    for (int p = 0; p < 8; ++p) {
        const float k0 = acc2[2 * p], k1 = acc2[2 * p + 1];
        if (M == 1)      Up[p] = packbf(k0, k1);
        else if (M == 2) Vp[p] = packbf(k0, k1);
        else if (M == 3) {
            const float u0 = bplo(Up[p]), u1 = bphi(Up[p]);
            const float v0 = bplo(Vp[p]), v1 = bphi(Vp[p]);
            Up[p] = packbf(fmaf(3.f, v0 + k0, u0), fmaf(3.f, v1 + k1, u1));
            Vp[p] = packbf(u0 - v0 + k0, u1 - v1 + k1);
        } else {
            const float u0 = bplo(Up[p]), u1 = bphi(Up[p]);
            y[2 * p]     = fmaf(HS * 0.125f, u0 + k0, y[2 * p]);
            y[2 * p + 1] = fmaf(HS * 0.125f, u1 + k1, y[2 * p + 1]);
        }
    }
}

__global__ __launch_bounds__(256) void gnode_kernel(
    const float* __restrict__ x, const uint4* __restrict__ wfr,
    const float* __restrict__ b1, const float* __restrict__ b2,
    const float* __restrict__ bl, float* __restrict__ out, int n)
{
    __shared__ uint4 argx[8][64];    // 8KB: arg window exchange
    __shared__ uint4 hx[8][64];      // 8KB: hidden window exchange
    __shared__ float s_bf[256];      // 1KB: b1 [0..127], b2 [128..255]

    const int tid  = threadIdx.x;
    const int lane = tid & 63;
    const int wid  = tid >> 6;       // 0..3: which 32-out-ch slice
    const int hw   = lane >> 5;      // half-wave
    const int c32  = lane & 31;
    const int row  = blockIdx.x * 32 + c32;   // this lane's batch row
    const int rowc = row < n ? row : n - 1;

    s_bf[tid] = (tid < 128) ? b1[tid] : b2[tid - 128];

    // ---- weights: wid-relative window order kl -> (2wid+kl)&7
    bf16x8 w1r[8], w2r[8];
    #pragma unroll
    for (int kl = 0; kl < 8; ++kl) {
        const int kg = (2 * wid + kl) & 7;
        w1r[kl] = bc8(wfr[(wid * 8 + kg) * 64 + lane]);
        w2r[kl] = bc8(wfr[(32 + wid * 8 + kg) * 64 + lane]);
    }

    // ---- hoisted LDS pointers
    uint4* myA = &argx[2 * wid][lane];       // own windows 2wid, 2wid+1
    uint4* myH = &hx[2 * wid][lane];
    const uint4* oa[6];
    const uint4* oh[6];
    #pragma unroll
    for (int kl = 2; kl < 8; ++kl) {
        const int kg = (2 * wid + kl) & 7;
        oa[kl - 2] = &argx[kg][lane];
        oh[kl - 2] = &hx[kg][lane];
    }
    const float* sbf1 = &s_bf[32 * wid + 4 * hw];
    const float* sbf2 = &s_bf[128 + 32 * wid + 4 * hw];

    // ---- state: 16 elems, ch_local = (e&3) + 8*(e>>2) + 4*hw (reg order)
    float y[16];
    {
        const f32x4* x4 = (const f32x4*)x;
        #pragma unroll
        for (int q = 0; q < 4; ++q) {
            const f32x4 v = x4[(size_t)rowc * 32 + 8 * wid + 2 * q + hw];
            #pragma unroll
            for (int r = 0; r < 4; ++r) y[4 * q + r] = v[r];
        }
    }
    __syncthreads();

    unsigned Up[8], Vp[8];

    #pragma unroll 1
    for (int st = 0; st < 10; ++st) {
        feval<1>(w1r, w2r, sbf1, sbf2, myA, oa, myH, oh, y, Up, Vp);
        feval<2>(w1r, w2r, sbf1, sbf2, myA, oa, myH, oh, y, Up, Vp);
        feval<3>(w1r, w2r, sbf1, sbf2, myA, oa, myH, oh, y, Up, Vp);
        feval<4>(w1r, w2r, sbf1, sbf2, myA, oa, myH, oh, y, Up, Vp);
    }

    // ---- epilogue: out^T = Wl^T y^T + bl.  All waves publish y windows;
    //      waves 0,1 compute out-ch [32wid,+32).
    {
        bf16x8 y0, y1;
        #pragma unroll
        for (int j = 0; j < 8; ++j) { y0[j] = bf16s(y[j]); y1[j] = bf16s(y[8 + j]); }
        myA[0]  = __builtin_bit_cast(uint4, y0);
        myA[64] = __builtin_bit_cast(uint4, y1);
    }
    __syncthreads();
    if (wid < 2) {
        f32x16 ao;
        {
            const f32x4* bl4 = (const f32x4*)bl;
            #pragma unroll
            for (int q = 0; q < 4; ++q) {
                const f32x4 b = bl4[8 * wid + 2 * q + hw];
                #pragma unroll
                for (int r = 0; r < 4; ++r) ao[4 * q + r] = b[r];
            }
        }
        #pragma unroll
        for (int kw = 0; kw < 8; ++kw)
            ao = MFMA32(bc8(wfr[(64 + wid * 8 + kw) * 64 + lane]),
                        bc8(argx[kw][lane]), ao, 0, 0, 0);
        if (row < n) {
            f32x4* out4 = (f32x4*)out;
            #pragma unroll
            for (int q = 0; q < 4; ++q) {
                f32x4 v;
                #pragma unroll
                for (int r = 0; r < 4; ++r) v[r] = ao[4 * q + r];
                out4[(size_t)row * 16 + 8 * wid + 2 * q + hw] = v;
            }
        }
    }
}

// ---- prep: A-frag-linear bf16 weights into d_ws (32x32x16 layout) ----
// A-frag (32x16): lane l, elem j: row(out-ch) = MB*32 + (l&31),
//                                 k = kw*16 + 8*(j>>2) + 4*(l>>5) + (j&3)
// wfr[f*64+lane]: f 0..31 = W1 (MB=f>>3, kw=f&7), 32..63 = W2, 64..79 = Wl.
__global__ void prep_kernel(const float* __restrict__ W1, const float* __restrict__ W2,
                            const float* __restrict__ Wl, uint4* __restrict__ wfr)
{
    int t = blockIdx.x * 256 + threadIdx.x;
    if (t >= 80 * 64) return;
    int f = t >> 6, lane = t & 63;
    int hw = lane >> 5, c = lane & 31;
    const float* W; int mb, kw, cols;
    if (f < 32)      { W = W1; mb = f >> 3;        kw = f & 7;        cols = 128; }
    else if (f < 64) { W = W2; mb = (f - 32) >> 3; kw = (f - 32) & 7; cols = 128; }
    else             { W = Wl; mb = (f - 64) >> 3; kw = (f - 64) & 7; cols = 64;  }
    int col = mb * 32 + c;               // output-channel (A row)
    unsigned short v[8];
    #pragma unroll
    for (int j = 0; j < 8; ++j) {
        int k = kw * 16 + 8 * (j >> 2) + 4 * hw + (j & 3);
        v[j] = (unsigned short)__builtin_bit_cast(short, (__bf16)W[k * cols + col]);
    }
    uint4 o;
    o.x = (unsigned)v[0] | ((unsigned)v[1] << 16);
    o.y = (unsigned)v[2] | ((unsigned)v[3] << 16);
    o.z = (unsigned)v[4] | ((unsigned)v[5] << 16);
    o.w = (unsigned)v[6] | ((unsigned)v[7] << 16);
    wfr[t] = o;
}

extern "C" void kernel_launch(void* const* d_in, const int* in_sizes, int n_in,
                              void* d_out, int out_size, void* d_ws, size_t ws_size,
                              hipStream_t stream)
{
    const float* x  = (const float*)d_in[0];
    const float* W1 = (const float*)d_in[1];
    const float* b1 = (const float*)d_in[2];
    const float* W2 = (const float*)d_in[3];
    const float* b2 = (const float*)d_in[4];
    const float* Wl = (const float*)d_in[5];
    const float* bl = (const float*)d_in[6];

    const int n = in_sizes[0] / 128;

    uint4* wfr = (uint4*)d_ws;                       // 80*64*16 = 81920 B

    prep_kernel<<<20, 256, 0, stream>>>(W1, W2, Wl, wfr);

    const int nb = (n + 31) / 32;            // 32 rows per block (4 waves)
    gnode_kernel<<<nb, 256, 0, stream>>>(x, wfr, b1, b2, bl, (float*)d_out, n);
}

// Round 22
// 472.525 us; speedup vs baseline: 1.1698x; 1.1698x over previous
//
#include <hip/hip_runtime.h>
#include <hip/hip_bf16.h>

// GNODE fully fused: y' = relu(y@W1+b1)@W2+b2, RK4(3/8) x10 steps (h=0.1),
// out = y@Wl+bl.  N=200000 rows, 128 ch, 64 out ch.
//
// FINAL (= r17, session best: 466us bench, 530us dispatch).  4-way channel
// split, 16x16x32 MFMA, fp32 state.  Structure-search summary (21 rounds):
//   - weights-in-LDS (r7): LDS-BW bound at ~33% MfmaUtil (1KB frag/MFMA).
//   - forced AGPR pinning (r9/r11): prologue spill storm / data corruption.
//   - dual row-tile (r10/r15/r18): reg blowup -> occupancy loss, 3x measured.
//   - 8-way split (r19): b64 half-frag exchange = 3.2e7 bank conflicts.
//   - 32x32x16 shape (r20/r21): +15% MFMA rate < -33% occupancy (2 vs 3
//     waves/SIMD); bf16-packing the state couldn't recover the wave.
// This config: VGPR 72 arch + ~80 AGPR (weights land in AGPRs naturally),
// 3 waves/SIMD, zero spill (FETCH/WRITE = exactly in+out), zero bank
// conflicts, MfmaUtil 46.5 / VALU-only ~8% / rest = barrier+LDS-latency
// chain intrinsic to the cross-wave exchange.
//
// Block = 256 thr = 4 waves, 16 rows; wave wid owns out-ch [32wid,+32) of
// both layers; weights 8+8 A-frags = 64 regs.  B-frag kb == wave kb's 8
// state elems -> exchange = write own frag, read other 3 per matmul.
//
// State recurrences (template<MODE>):
//   M1: U<-k1   M2: V<-k2   M3: U<-U+3(V+k3), V<-U-V+k3   M4: y+=h/8(U+k4)
// Layout identity (mfma_f32_16x16x32_bf16, HW-verified m89):
//   D:      ch = 16*MB + 4*(lane>>4) + r,               batch = lane&15
//   B-frag: ch = 32*kb + 16*(j>>2) + 4*(lane>>4)+(j&3),  batch = lane&15
// => frag[kb][j] = state[8*kb + j]; wave wid owns MB {2wid,2wid+1}, i.e.
//    state elems [8wid, 8wid+8).  All lane-local.
// Barrier safety: 2 barriers/feval on alternating buffers (argx, hx).

typedef __attribute__((ext_vector_type(8))) short bf16x8;
typedef __attribute__((ext_vector_type(4))) float f32x4;

constexpr float HS = 0.1f;

__device__ __forceinline__ short bf16s(float f) {
    return __builtin_bit_cast(short, (__bf16)f);      // -> v_cvt_pk_bf16_f32 (paired)
}
__device__ __forceinline__ bf16x8 bc8(uint4 u) { return __builtin_bit_cast(bf16x8, u); }

#define MFMA_BF16 __builtin_amdgcn_mfma_f32_16x16x32_bf16

// Own B-frag (8 elems) from fp32 y/U/V, RK4 combo fused per mode.
template<int M>
__device__ __forceinline__ bf16x8 build_frag(const float (&y)[8], const float (&U)[8],
                                             const float (&V)[8]) {
    bf16x8 f;
    #pragma unroll
    for (int j = 0; j < 8; ++j) {
        float v;
        if (M == 1)      v = y[j];
        else if (M == 2) v = fmaf(HS * (1.f / 3.f), U[j], y[j]);
        else if (M == 3) v = fmaf(-HS * (1.f / 3.f), U[j], fmaf(HS, V[j], y[j]));
        else             v = fmaf(HS, V[j], y[j]);
        f[j] = bf16s(v);
    }
    return f;
}

// One f-eval for this wave's 32-out-ch quarter.  Weight frags wid-relative:
// index f = mb*4 + kl, kl 0 = own kb, kl 1..3 = (wid+kl)&3.
template<int M>
__device__ __forceinline__ void feval(const bf16x8 (&w1r)[8], const bf16x8 (&w2r)[8],
                                      const float* __restrict__ sbf1,
                                      const float* __restrict__ sbf2,
                                      uint4* __restrict__ my_arg,
                                      const uint4* __restrict__ oa1,
                                      const uint4* __restrict__ oa2,
                                      const uint4* __restrict__ oa3,
                                      uint4* __restrict__ my_h,
                                      const uint4* __restrict__ oh1,
                                      const uint4* __restrict__ oh2,
                                      const uint4* __restrict__ oh3,
                                      float (&y)[8], float (&U)[8], float (&V)[8])
{
    // ---- own arg frag -> LDS; bias init overlaps the barrier
    const bf16x8 a0 = build_frag<M>(y, U, V);
    *my_arg = __builtin_bit_cast(uint4, a0);
    f32x4 acc[2];
    acc[0] = *(const f32x4*)&sbf1[0];
    acc[1] = *(const f32x4*)&sbf1[16];
    __syncthreads();
    const bf16x8 a1 = bc8(*oa1);
    const bf16x8 a2 = bc8(*oa2);
    const bf16x8 a3 = bc8(*oa3);

    // ---- matmul1: 8 MFMA (kl0 = own frag from regs)
    __builtin_amdgcn_s_setprio(1);
    acc[0] = MFMA_BF16(w1r[0], a0, acc[0], 0, 0, 0);
    acc[1] = MFMA_BF16(w1r[4], a0, acc[1], 0, 0, 0);
    acc[0] = MFMA_BF16(w1r[1], a1, acc[0], 0, 0, 0);
    acc[1] = MFMA_BF16(w1r[5], a1, acc[1], 0, 0, 0);
    acc[0] = MFMA_BF16(w1r[2], a2, acc[0], 0, 0, 0);
    acc[1] = MFMA_BF16(w1r[6], a2, acc[1], 0, 0, 0);
    acc[0] = MFMA_BF16(w1r[3], a3, acc[0], 0, 0, 0);
    acc[1] = MFMA_BF16(w1r[7], a3, acc[1], 0, 0, 0);
    __builtin_amdgcn_s_setprio(0);

    // ---- relu -> own h frag (h elem j = acc[j>>2][j&3]; adjacent pairs packable)
    bf16x8 hb;
    #pragma unroll
    for (int j = 0; j < 8; ++j)
        hb[j] = bf16s(fmaxf(acc[j >> 2][j & 3], 0.f));
    *my_h = __builtin_bit_cast(uint4, hb);
    f32x4 acc2[2];
    acc2[0] = *(const f32x4*)&sbf2[0];
    acc2[1] = *(const f32x4*)&sbf2[16];
    __syncthreads();
    const bf16x8 h1 = bc8(*oh1);
    const bf16x8 h2 = bc8(*oh2);
    const bf16x8 h3 = bc8(*oh3);

    // ---- matmul2: 8 MFMA
    __builtin_amdgcn_s_setprio(1);
    acc2[0] = MFMA_BF16(w2r[0], hb, acc2[0], 0, 0, 0);
    acc2[1] = MFMA_BF16(w2r[4], hb, acc2[1], 0, 0, 0);
    acc2[0] = MFMA_BF16(w2r[1], h1, acc2[0], 0, 0, 0);
    acc2[1] = MFMA_BF16(w2r[5], h1, acc2[1], 0, 0, 0);
    acc2[0] = MFMA_BF16(w2r[2], h2, acc2[0], 0, 0, 0);
    acc2[1] = MFMA_BF16(w2r[6], h2, acc2[1], 0, 0, 0);
    acc2[0] = MFMA_BF16(w2r[3], h3, acc2[0], 0, 0, 0);
    acc2[1] = MFMA_BF16(w2r[7], h3, acc2[1], 0, 0, 0);
    __builtin_amdgcn_s_setprio(0);

    // ---- mode-fused writeback (e = 4*mb + r, all fp32)
    #pragma unroll
    for (int e = 0; e < 8; ++e) {
        const float k = acc2[e >> 2][e & 3];
        if (M == 1)      U[e] = k;
        else if (M == 2) V[e] = k;
        else if (M == 3) {
            const float u = U[e], v = V[e];
            U[e] = fmaf(3.f, v + k, u);
            V[e] = u - v + k;
        } else {
            y[e] = fmaf(HS * 0.125f, U[e] + k, y[e]);
        }
    }
}

__global__ __launch_bounds__(256) void gnode_kernel(
    const float* __restrict__ x, const uint4* __restrict__ wfr,
    const float* __restrict__ b1, const float* __restrict__ b2,
    const float* __restrict__ bl, float* __restrict__ out, int n)
{
    __shared__ uint4 argx[4][64];    // 4KB: arg B-frag exchange (slot kb)
    __shared__ uint4 hx[4][64];      // 4KB: hidden B-frag exchange
    __shared__ float s_bf[256];      // 1KB: b1 [0..127], b2 [128..255]

    const int tid  = threadIdx.x;
    const int lane = tid & 63;
    const int wid  = tid >> 6;       // 0..3: which 32-out-ch quarter this wave owns
    const int g    = lane >> 4;
    const int c16  = lane & 15;
    const int row  = blockIdx.x * 16 + c16;   // this lane's batch row
    const int rowc = row < n ? row : n - 1;

    if (wid < 2) s_bf[tid & 127]         = b1[tid & 127];   // waves 0,1 write b1
    else         s_bf[128 + (tid & 127)] = b2[tid & 127];   // waves 2,3 write b2

    // ---- weights: this wave's quarters, wid-RELATIVE kb order kl -> (wid+kl)&3
    bf16x8 w1r[8], w2r[8];
    #pragma unroll
    for (int f = 0; f < 8; ++f) {
        const int mb = f >> 2, kl = f & 3;
        const int kg = (wid + kl) & 3;
        w1r[f] = bc8(wfr[((2 * wid + mb) * 4 + kg) * 64 + lane]);
        w2r[f] = bc8(wfr[(32 + (2 * wid + mb) * 4 + kg) * 64 + lane]);
    }

    // ---- hoisted LDS pointers
    uint4*       my_arg = &argx[wid][lane];
    const uint4* oa1    = &argx[(wid + 1) & 3][lane];
    const uint4* oa2    = &argx[(wid + 2) & 3][lane];
    const uint4* oa3    = &argx[(wid + 3) & 3][lane];
    uint4*       my_h   = &hx[wid][lane];
    const uint4* oh1    = &hx[(wid + 1) & 3][lane];
    const uint4* oh2    = &hx[(wid + 2) & 3][lane];
    const uint4* oh3    = &hx[(wid + 3) & 3][lane];
    const float* sbf1   = &s_bf[32 * wid + 4 * g];
    const float* sbf2   = &s_bf[128 + 32 * wid + 4 * g];

    // ---- state: this wave's 8 elems (ch = 32wid + 16t + 4g + r, t = e>>2)
    float y[8];
    {
        const f32x4* x4 = (const f32x4*)x;
        const f32x4 v0 = x4[(size_t)rowc * 32 + 8 * wid + g];
        const f32x4 v1 = x4[(size_t)rowc * 32 + 8 * wid + 4 + g];
        #pragma unroll
        for (int r = 0; r < 4; ++r) { y[r] = v0[r]; y[4 + r] = v1[r]; }
    }
    __syncthreads();

    float U[8], V[8];

    #pragma unroll 1
    for (int st = 0; st < 10; ++st) {
        feval<1>(w1r, w2r, sbf1, sbf2, my_arg, oa1, oa2, oa3, my_h, oh1, oh2, oh3, y, U, V);
        feval<2>(w1r, w2r, sbf1, sbf2, my_arg, oa1, oa2, oa3, my_h, oh1, oh2, oh3, y, U, V);
        feval<3>(w1r, w2r, sbf1, sbf2, my_arg, oa1, oa2, oa3, my_h, oh1, oh2, oh3, y, U, V);
        feval<4>(w1r, w2r, sbf1, sbf2, my_arg, oa1, oa2, oa3, my_h, oh1, oh2, oh3, y, U, V);
    }

    // ---- epilogue: out^T = Wl^T y^T + bl (wave computes out-ch [16wid,+16))
    bf16x8 yf;
    #pragma unroll
    for (int j = 0; j < 8; ++j) yf[j] = bf16s(y[j]);
    *my_arg = __builtin_bit_cast(uint4, yf);
    __syncthreads();
    const bf16x8 yf1 = bc8(*oa1);
    const bf16x8 yf2 = bc8(*oa2);
    const bf16x8 yf3 = bc8(*oa3);

    f32x4 ao = ((const f32x4*)bl)[wid * 4 + g];          // bl[16wid + 4g + r]
    {
        const int fb = 64 + wid * 4;                     // Wl frag base, global kb order
        ao = MFMA_BF16(bc8(wfr[(fb + ((wid + 0) & 3)) * 64 + lane]), yf,  ao, 0, 0, 0);
        ao = MFMA_BF16(bc8(wfr[(fb + ((wid + 1) & 3)) * 64 + lane]), yf1, ao, 0, 0, 0);
        ao = MFMA_BF16(bc8(wfr[(fb + ((wid + 2) & 3)) * 64 + lane]), yf2, ao, 0, 0, 0);
        ao = MFMA_BF16(bc8(wfr[(fb + ((wid + 3) & 3)) * 64 + lane]), yf3, ao, 0, 0, 0);
    }
    if (row < n)
        ((f32x4*)out)[(size_t)row * 16 + wid * 4 + g] = ao;   // out[row][16wid+4g+r]
}

// ---- prep: A-frag-linear bf16 weights into d_ws ----
// A-frag (16x32): lane l, elem j:  row = l&15 (+16*MB),
//                                  k   = 32*kb + 16*(j>>2) + 4*(l>>4) + (j&3)
// wfr[f*64+lane] : f 0..31 = W1 (MB=f>>2,kb=f&3), 32..63 = W2, 64..79 = Wl.
__global__ void prep_kernel(const float* __restrict__ W1, const float* __restrict__ W2,
                            const float* __restrict__ Wl, uint4* __restrict__ wfr)
{
    int t = blockIdx.x * 256 + threadIdx.x;
    if (t >= 80 * 64) return;
    int f = t >> 6, lane = t & 63;
    int gq = lane >> 4, c = lane & 15;
    const float* W; int mb, kv, cols;
    if (f < 32)      { W = W1; mb = f >> 2;        kv = f & 3;        cols = 128; }
    else if (f < 64) { W = W2; mb = (f - 32) >> 2; kv = (f - 32) & 3; cols = 128; }
    else             { W = Wl; mb = (f - 64) >> 2; kv = (f - 64) & 3; cols = 64;  }
    int col = mb * 16 + c;               // output-channel (A row)
    unsigned short v[8];
    #pragma unroll
    for (int j = 0; j < 8; ++j) {
        int k = kv * 32 + (j >> 2) * 16 + gq * 4 + (j & 3);
        v[j] = (unsigned short)__builtin_bit_cast(short, (__bf16)W[k * cols + col]);
    }
    uint4 o;
    o.x = (unsigned)v[0] | ((unsigned)v[1] << 16);
    o.y = (unsigned)v[2] | ((unsigned)v[3] << 16);
    o.z = (unsigned)v[4] | ((unsigned)v[5] << 16);
    o.w = (unsigned)v[6] | ((unsigned)v[7] << 16);
    wfr[t] = o;
}

extern "C" void kernel_launch(void* const* d_in, const int* in_sizes, int n_in,
                              void* d_out, int out_size, void* d_ws, size_t ws_size,
                              hipStream_t stream)
{
    const float* x  = (const float*)d_in[0];
    const float* W1 = (const float*)d_in[1];
    const float* b1 = (const float*)d_in[2];
    const float* W2 = (const float*)d_in[3];
    const float* b2 = (const float*)d_in[4];
    const float* Wl = (const float*)d_in[5];
    const float* bl = (const float*)d_in[6];

    const int n = in_sizes[0] / 128;

    uint4* wfr = (uint4*)d_ws;                       // 80*64*16 = 81920 B

    prep_kernel<<<20, 256, 0, stream>>>(W1, W2, Wl, wfr);

    const int nb = (n + 15) / 16;            // 16 rows per block (4 waves)
    gnode_kernel<<<nb, 256, 0, stream>>>(x, wfr, b1, b2, bl, (float*)d_out, n);
}